// Round 12
// baseline (214.664 us; speedup 1.0000x reference)
//
#include <hip/hip_runtime.h>

typedef __bf16 bf16_t;
typedef __bf16 bf16x4_t __attribute__((ext_vector_type(4)));
typedef __bf16 bf16x8 __attribute__((ext_vector_type(8)));
typedef float f32x4 __attribute__((ext_vector_type(4)));

#define NH 8
#define DH 32
#define QL 256
#define KL 256
#define CIN 64
#define HD 256  // NH*DH

__device__ __forceinline__ bf16_t f2bf(float x) { return (bf16_t)x; }

__device__ __forceinline__ f32x4 mfma16(bf16x8 a, bf16x8 b, f32x4 c) {
    return __builtin_amdgcn_mfma_f32_16x16x32_bf16(a, b, c, 0, 0, 0);
}

// raw v_exp_f32: D = 2^S0
__device__ __forceinline__ float exp2_raw(float x) {
    float r;
    asm("v_exp_f32 %0, %1" : "=v"(r) : "v"(x));
    return r;
}

// ---------------------------------------------------------------------------
// pack_w: one-time repack of Wq/Wk/Wv/Wo into fragment-native bf16 layout.
// (identical to r11: proj B-frags; WoF delta-packed for lane-local O A-frag)
__launch_bounds__(256)
__global__ void pack_w(const float* __restrict__ Wq, const float* __restrict__ Wk,
                       const float* __restrict__ Wv, const float* __restrict__ Wo,
                       bf16_t* __restrict__ WqF, bf16_t* __restrict__ WkF,
                       bf16_t* __restrict__ WvF, bf16_t* __restrict__ WoF) {
    const int h = blockIdx.x;
    const int tid = threadIdx.x, lane = tid & 63, w = tid >> 6;
    const int quad = lane >> 4, l16 = lane & 15;
    if (w < 3) {
        const float* __restrict__ W = (w == 0) ? Wq : (w == 1 ? Wk : Wv);
        bf16_t* __restrict__ F = (w == 0) ? WqF : (w == 1 ? WkF : WvF);
#pragma unroll
        for (int nt = 0; nt < 2; ++nt)
#pragma unroll
            for (int ks = 0; ks < 2; ++ks) {
                bf16x8 f;
#pragma unroll
                for (int j = 0; j < 8; ++j)
                    f[j] = f2bf(W[(ks * 32 + quad * 8 + j) * HD + h * DH + nt * 16 + l16]);
                *(bf16x8*)&F[(size_t)((h * 4 + nt * 2 + ks) * 512) + lane * 8] = f;
            }
    } else {
#pragma unroll
        for (int nt = 0; nt < 4; ++nt) {
            bf16x8 f;
#pragma unroll
            for (int j = 0; j < 8; ++j)
                f[j] = f2bf(Wo[(h * DH + (j >> 2) * 16 + quad * 4 + (j & 3)) * CIN +
                               nt * 16 + l16]);
            *(bf16x8*)&WoF[(size_t)((h * 4 + nt) * 512) + lane * 8] = f;
        }
    }
}

// ---------------------------------------------------------------------------
// fused_w8: r11's dataflow at DOUBLE the wave count. 512 blocks x 512 thr;
// waves w and w+4 share q-tile (w&3) and SPLIT the kv axis (128 each).
// r11 post-mortem: 62us floor = 2 barrier-correlated waves/SIMD; ~53% dead
// time with all issue counters low. Same LDS (77.3 KB) now hosts 8 waves ->
// 16 waves/CU = 4/SIMD.
//  - QK+softmax duplicated per pair (MFMA is 12%-idle; bias loads are NOT
//    duplicated: each wave loads only its kv-half's bias columns).
//  - PV/projKV/staging halved per wave; kv-partial O flows LINEARLY through
//    outproj into acc; halves combined ONCE at kernel end via LDS scratch.
//  - softmax: one mid-phase barrier for the cross-pair max exchange; the
//    SUM exchange is free -- outproj(h) moves to phase h+1 start and reads
//    partner's partial sum (parity-buffered sSum) after the phase barrier.
//  - all fragment/LDS index math r11-verbatim (pi-packed sK[256][40], sVT,
//    sigma-PV, delta-outproj, exp2 softmax, bias-in-PV interleave).
__launch_bounds__(512, 4)
__global__ void fused_w8(const float* __restrict__ Xq, const float* __restrict__ Xkv,
                         const float* __restrict__ Mask, const float* __restrict__ Bias,
                         const bf16_t* __restrict__ WqF, const bf16_t* __restrict__ WkF,
                         const bf16_t* __restrict__ WvF, const bf16_t* __restrict__ WoF,
                         const float* __restrict__ Bo, float* __restrict__ Out) {
    const int b = blockIdx.x;
    const int s = b & 127, qq = b >> 7;   // s fastest: same-s blocks share an XCD
    const int tid = threadIdx.x, lane = tid & 63, w = tid >> 6;  // w 0..7
    const int quad = lane >> 4, l16 = lane & 15;
    const int wq = w & 3, hv = w >> 2;    // q-slot, kv-half
    const int tg = qq * 4 + wq;           // this wave's q-tile (16 rows)
    const int ct0 = hv * 8;               // global kv-tile base (8 tiles/half)
    const int cc0 = hv * 4;               // global PV chunk base (4 chunks/half)
    const f32x4 vzero = {0.f, 0.f, 0.f, 0.f};
    constexpr float L2E = 1.4426950408889634f;

    __shared__ __attribute__((aligned(16))) bf16_t sK[2][KL * 40];   // 40.0 KB dbuf
    __shared__ __attribute__((aligned(16))) bf16_t sVT[2][DH][264];  // 33.0 KB dbuf
    __shared__ __attribute__((aligned(16))) float sMask[KL];         //  1.0 KB
    __shared__ float sRed[8][16];                                    //  0.5 KB pmax
    __shared__ float sSum[2][8][16];                                 //  1.0 KB psum

    if (tid < 64) {
        const f32x4 m4 = *(const f32x4*)&Mask[s * KL + tid * 4];
        f32x4 mm;
#pragma unroll
        for (int j = 0; j < 4; ++j) mm[j] = (m4[j] - 1.0f) * (1.0e9f * L2E);
        *(f32x4*)&sMask[tid * 4] = mm;
    }

    // ---- X fragments: wave stages kv-tiles {2w, 2w+1} (2 not 4) ----
    bf16x8 xk[2][2];
#pragma unroll
    for (int t = 0; t < 2; ++t) {
        const int row = (2 * w + t) * 16 + l16;
        const float* src = &Xkv[(size_t)(s * QL + row) * CIN];
#pragma unroll
        for (int ks = 0; ks < 2; ++ks) {
            const f32x4 lo = *(const f32x4*)&src[ks * 32 + quad * 8];
            const f32x4 hi = *(const f32x4*)&src[ks * 32 + quad * 8 + 4];
            bf16x8 f;
#pragma unroll
            for (int j = 0; j < 4; ++j) { f[j] = f2bf(lo[j]); f[4 + j] = f2bf(hi[j]); }
            xk[t][ks] = f;
        }
    }
    bf16x8 xq[2];  // Xq frags for q-tile tg, pre-scaled (1/sqrt(32))*log2e
    {
        const int row = tg * 16 + l16;
        const float* src = &Xq[(size_t)(s * QL + row) * CIN];
        const float qs = 0.17677669529663687f * L2E;
#pragma unroll
        for (int ks = 0; ks < 2; ++ks) {
            const f32x4 lo = *(const f32x4*)&src[ks * 32 + quad * 8];
            const f32x4 hi = *(const f32x4*)&src[ks * 32 + quad * 8 + 4];
            bf16x8 f;
#pragma unroll
            for (int j = 0; j < 4; ++j) {
                f[j] = f2bf(lo[j] * qs);
                f[4 + j] = f2bf(hi[j] * qs);
            }
            xq[ks] = f;
        }
    }

    // K/V projection: this wave stages kv-tiles {2w, 2w+1} (r11-verbatim math)
    auto projKV = [&](int h, int buf) {
        bf16x8 bk[2][2], bv[2][2];
#pragma unroll
        for (int nt = 0; nt < 2; ++nt)
#pragma unroll
            for (int ks = 0; ks < 2; ++ks) {
                bk[nt][ks] = *(const bf16x8*)&WkF[(size_t)((h * 4 + nt * 2 + ks) * 512) + lane * 8];
                bv[nt][ks] = *(const bf16x8*)&WvF[(size_t)((h * 4 + nt * 2 + ks) * 512) + lane * 8];
            }
#pragma unroll
        for (int t = 0; t < 2; ++t) {
            const int row = (2 * w + t) * 16 + l16;
#pragma unroll
            for (int nt = 0; nt < 2; ++nt) {
                f32x4 c = mfma16(bk[nt][0], xk[t][0], vzero);
                c = mfma16(bk[nt][1], xk[t][1], c);
                bf16x4_t p4;
#pragma unroll
                for (int r = 0; r < 4; ++r) p4[r] = f2bf(c[r]);
                *(bf16x4_t*)&sK[buf][row * 40 + quad * 8 + nt * 4] = p4;
            }
        }
#pragma unroll
        for (int t = 0; t < 2; ++t) {
            const int c0v = (2 * w + t) * 16 + quad * 4;
#pragma unroll
            for (int nt = 0; nt < 2; ++nt) {
                f32x4 c = mfma16(xk[t][0], bv[nt][0], vzero);
                c = mfma16(xk[t][1], bv[nt][1], c);
                bf16x4_t p4;
#pragma unroll
                for (int r = 0; r < 4; ++r) p4[r] = f2bf(c[r]);
                *(bf16x4_t*)&sVT[buf][nt * 16 + l16][c0v] = p4;
            }
        }
    };
    // Q projection, register-only (r11-verbatim; duplicated across the pair)
    auto projQ = [&](int h) -> bf16x8 {
        bf16x8 bq[2][2];
#pragma unroll
        for (int nt = 0; nt < 2; ++nt)
#pragma unroll
            for (int ks = 0; ks < 2; ++ks)
                bq[nt][ks] = *(const bf16x8*)&WqF[(size_t)((h * 4 + nt * 2 + ks) * 512) + lane * 8];
        bf16x8 q;
#pragma unroll
        for (int nt = 0; nt < 2; ++nt) {
            f32x4 c = mfma16(bq[nt][0], xq[0], vzero);
            c = mfma16(bq[nt][1], xq[1], c);
#pragma unroll
            for (int r = 0; r < 4; ++r) q[nt * 4 + r] = f2bf(c[r]);
        }
        return q;
    };
    // va pair for PV chunk c (global index; r11-verbatim sigma layout)
    auto loadVA = [&](int p, int c, bf16x8& v0, bf16x8& v1) {
        const bf16x4_t a00 = *(const bf16x4_t*)&sVT[p][l16][c * 32 + quad * 4];
        const bf16x4_t a01 = *(const bf16x4_t*)&sVT[p][l16][c * 32 + 16 + quad * 4];
        const bf16x4_t a10 = *(const bf16x4_t*)&sVT[p][16 + l16][c * 32 + quad * 4];
        const bf16x4_t a11 = *(const bf16x4_t*)&sVT[p][16 + l16][c * 32 + 16 + quad * 4];
#pragma unroll
        for (int j = 0; j < 4; ++j) {
            v0[j] = a00[j];
            v0[4 + j] = a01[j];
            v1[j] = a10[j];
            v1[4 + j] = a11[j];
        }
    };

    f32x4 acc[4];  // kv-partial output accumulator (combined once at end)
#pragma unroll
    for (int nt = 0; nt < 4; ++nt) acc[nt] = vzero;
    f32x4 ot0 = vzero, ot1 = vzero;  // O^T partials, carried across barrier
    float psum = 0.f;                // own-half softmax sum, carried
    bf16x8 bwo[4];                   // delta-packed Wo frags, carried

    // ---- prologue: bias(0, own half) in flight; K/V/Q(0) ----
    f32x4 sv[8];
    {
        const float* bb = &Bias[(size_t)(tg * 16 + l16) * KL];
#pragma unroll
        for (int c = 0; c < 8; ++c)
            sv[c] = *(const f32x4*)&bb[(ct0 + c) * 16 + quad * 4];
    }
    projKV(0, 0);
    bf16x8 qfr = projQ(0);
    __syncthreads();  // buf0 + sMask visible
#pragma unroll
    for (int c = 0; c < 8; ++c) {
        const f32x4 m4 = *(const f32x4*)&sMask[(ct0 + c) * 16 + quad * 4];
#pragma unroll
        for (int r = 0; r < 4; ++r) sv[c][r] = sv[c][r] * L2E + m4[r];
    }

#pragma unroll 1
    for (int h = 0; h < NH; ++h) {
        const int p = h & 1;

        // ---- outproj(h-1): partner psum now visible (phase barrier passed) ----
        if (h > 0) {
            const float rs = 1.0f / (psum + sSum[p ^ 1][w ^ 4][l16]);
            bf16x8 af;
#pragma unroll
            for (int r = 0; r < 4; ++r) {
                af[r] = f2bf(ot0[r] * rs);
                af[4 + r] = f2bf(ot1[r] * rs);
            }
#pragma unroll
            for (int nt = 0; nt < 4; ++nt) acc[nt] = mfma16(af, bwo[nt], acc[nt]);
        }

        // ---- QK(h), own kv-half: 8 MFMAs, bias+mask rides C ----
#pragma unroll
        for (int c = 0; c < 8; ++c) {
            const bf16x8 ak = *(const bf16x8*)&sK[p][((ct0 + c) * 16 + l16) * 40 + quad * 8];
            sv[c] = mfma16(ak, qfr, sv[c]);
        }
        // partial max over own 128 kv (tree + quad shfl)
        f32x4 vmx = sv[0];
#pragma unroll
        for (int c = 1; c < 8; ++c)
#pragma unroll
            for (int r = 0; r < 4; ++r) vmx[r] = fmaxf(vmx[r], sv[c][r]);
        float pmax = fmaxf(fmaxf(vmx[0], vmx[1]), fmaxf(vmx[2], vmx[3]));
        pmax = fmaxf(pmax, __shfl_xor(pmax, 16, 64));
        pmax = fmaxf(pmax, __shfl_xor(pmax, 32, 64));
        if (lane < 16) sRed[w][lane] = pmax;

        __syncthreads();  // B_mid: max exchange

        const float gmax = fmaxf(pmax, sRed[w ^ 4][l16]);

        // ---- proj(h+1) into buf 1-p: independent filler over exp/PV ----
        if (h + 1 < NH) projKV(h + 1, p ^ 1);

        // ---- Wo frags for outproj(h) at next phase start ----
#pragma unroll
        for (int nt = 0; nt < 4; ++nt)
            bwo[nt] = *(const bf16x8*)&WoF[(size_t)((h * 4 + nt) * 512) + lane * 8];

        // ---- exp + own-half sum ----
        f32x4 vsum = vzero;
#pragma unroll
        for (int c = 0; c < 8; ++c)
#pragma unroll
            for (int r = 0; r < 4; ++r) {
                const float e = exp2_raw(sv[c][r] - gmax);
                sv[c][r] = e;
                vsum[r] += e;
            }
        float ps = (vsum[0] + vsum[1]) + (vsum[2] + vsum[3]);
        ps += __shfl_xor(ps, 16, 64);
        ps += __shfl_xor(ps, 32, 64);
        psum = ps;
        if (lane < 16) sSum[p][w][lane] = ps;  // read by partner NEXT phase

        // ---- PV over own 4 chunks (sigma, LDS-free P), bias(h+1) interleaved ----
        const int hn = (h + 1) & 7;
        const float* bbn = &Bias[(size_t)(hn * QL + tg * 16 + l16) * KL];
        bf16x8 vc0, vc1;
        loadVA(p, cc0, vc0, vc1);
        ot0 = vzero;
        ot1 = vzero;
#pragma unroll
        for (int cl = 0; cl < 4; ++cl) {
            bf16x8 vn0, vn1;
            if (cl < 3) loadVA(p, cc0 + cl + 1, vn0, vn1);
            bf16x8 pf;
#pragma unroll
            for (int j = 0; j < 4; ++j) {
                pf[j] = f2bf(sv[2 * cl][j]);
                pf[4 + j] = f2bf(sv[2 * cl + 1][j]);
            }
            // dead slots -> refill with next head's bias (own half only)
            sv[2 * cl] = *(const f32x4*)&bbn[(ct0 + 2 * cl) * 16 + quad * 4];
            sv[2 * cl + 1] = *(const f32x4*)&bbn[(ct0 + 2 * cl + 1) * 16 + quad * 4];
            ot0 = mfma16(vc0, pf, ot0);
            ot1 = mfma16(vc1, pf, ot1);
            vc0 = vn0;
            vc1 = vn1;
        }

        // ---- tail: Q(h+1) register-only; fold mask into resident bias ----
        if (h + 1 < NH) {
            qfr = projQ(h + 1);
#pragma unroll
            for (int c = 0; c < 8; ++c) {
                const f32x4 m4 = *(const f32x4*)&sMask[(ct0 + c) * 16 + quad * 4];
#pragma unroll
                for (int r = 0; r < 4; ++r) sv[c][r] = sv[c][r] * L2E + m4[r];
            }
        }

        __syncthreads();  // phase end: buf 1-p ready, sSum[p] visible
    }

    // ---- epilogue: outproj(7), then combine kv-halves via LDS scratch ----
    {
        const float rs = 1.0f / (psum + sSum[1][w ^ 4][l16]);  // h=7 -> parity 1
        bf16x8 af;
#pragma unroll
        for (int r = 0; r < 4; ++r) {
            af[r] = f2bf(ot0[r] * rs);
            af[4 + r] = f2bf(ot1[r] * rs);
        }
#pragma unroll
        for (int nt = 0; nt < 4; ++nt) acc[nt] = mfma16(af, bwo[nt], acc[nt]);
    }
    float* scr = (float*)&sK[0][0];  // sK dead after final phase barrier
    if (hv == 1) {
#pragma unroll
        for (int nt = 0; nt < 4; ++nt)
#pragma unroll
            for (int r = 0; r < 4; ++r)
                scr[(wq * 64 + lane) * 16 + nt * 4 + r] = acc[nt][r];
    }
    __syncthreads();
    if (hv == 0) {
        const int orow = s * QL + tg * 16 + quad * 4;
#pragma unroll
        for (int nt = 0; nt < 4; ++nt) {
            const float bo = Bo[nt * 16 + l16];
#pragma unroll
            for (int r = 0; r < 4; ++r) {
                const float v = acc[nt][r] + scr[(wq * 64 + lane) * 16 + nt * 4 + r];
                Out[(size_t)(orow + r) * CIN + nt * 16 + l16] = v + bo;
            }
        }
    }
}

extern "C" void kernel_launch(void* const* d_in, const int* in_sizes, int n_in,
                              void* d_out, int out_size, void* d_ws, size_t ws_size,
                              hipStream_t stream) {
    const float* Xq   = (const float*)d_in[0];
    const float* Xkv  = (const float*)d_in[1];
    const float* Mask = (const float*)d_in[2];
    const float* Bias = (const float*)d_in[3];
    const float* Wq   = (const float*)d_in[4];
    const float* Wk   = (const float*)d_in[5];
    const float* Wv   = (const float*)d_in[6];
    const float* Wo   = (const float*)d_in[7];
    const float* Bo   = (const float*)d_in[8];
    float* Out = (float*)d_out;

    // 128 KB of fragment-native weights at the head of ws
    bf16_t* WqF = (bf16_t*)d_ws;
    bf16_t* WkF = WqF + 16384;
    bf16_t* WvF = WkF + 16384;
    bf16_t* WoF = WvF + 16384;

    pack_w<<<dim3(NH), 256, 0, stream>>>(Wq, Wk, Wv, Wo, WqF, WkF, WvF, WoF);
    fused_w8<<<dim3(512), 512, 0, stream>>>(Xq, Xkv, Mask, Bias,
                                            WqF, WkF, WvF, WoF, Bo, Out);
}